// Round 14
// baseline (74.856 us; speedup 1.0000x reference)
//
#include <hip/hip_runtime.h>
#include <hip/hip_bf16.h>
#include <math.h>

// Problem constants (from reference): D=256, H=8, C=32, H*C=256
#define DD 256
#define NHEAD 8
#define NEG_SLOPE 0.2f
#define CAP 64   // padded-CSR capacity; in-degree ~Poisson(16), P(>=64)~2e-18

typedef __attribute__((ext_vector_type(16))) float f32x16;
typedef __attribute__((ext_vector_type(8)))  short bf16x8;
typedef _Float16 h2 __attribute__((ext_vector_type(2)));

union Frag { bf16x8 v; uint4 u4; };
union HU4  { uint4 u4; h2 h[4]; };

__device__ inline uint f2bf(float f) {
    __hip_bfloat16 h = __float2bfloat16(f);
    return (uint)*(ushort*)&h;
}
__device__ inline ushort f2h(float f) {
    _Float16 h = (_Float16)f;
    return *(ushort*)&h;
}
__device__ inline h2 pkmax(h2 a, h2 b) {
    h2 d;
    asm("v_pk_max_f16 %0, %1, %2" : "=v"(d) : "v"(a), "v"(b));
    return d;
}
__device__ inline float hdot2(h2 a, h2 b, float c) {
#if __has_builtin(__builtin_amdgcn_fdot2)
    return __builtin_amdgcn_fdot2(a, b, c, false);
#else
    return c + (float)a.x * (float)b.x + (float)a.y * (float)b.y;
#endif
}

// ---------------- fused prep: zero counts | pack_x | pack_w -----------------
__global__ __launch_bounds__(256) void prep_kernel(const float* __restrict__ x,
                                                   const float* __restrict__ Wl,
                                                   const float* __restrict__ Wr,
                                                   ushort* __restrict__ pa,
                                                   ushort* __restrict__ pw,
                                                   int* __restrict__ counts,
                                                   int N, int Mpad) {
    int idx = blockIdx.x * 256 + threadIdx.x;
    if (idx < N) { counts[idx] = 0; return; }
    idx -= N;
    const int na = Mpad * 32;
    if (idx < na) {
        // pack x into MFMA A-fragment order (bf16): [tile][s16][mi][lane] x 16B
        int lane = idx & 63;
        int mi   = (idx >> 6) & 1;
        int s16  = (idx >> 7) & 15;
        int tile = idx >> 11;
        int m = tile * 64 + mi * 32 + (lane & 31);
        int g = lane >> 5;
        uint4 val = {0u, 0u, 0u, 0u};
        if (m < N) {
            const float* xp = x + (size_t)m * DD + s16 * 16 + g * 4;
            float4 f0 = *(const float4*)xp;
            float4 f1 = *(const float4*)(xp + 8);
            val.x = f2bf(f0.x) | (f2bf(f0.y) << 16);
            val.y = f2bf(f0.z) | (f2bf(f0.w) << 16);
            val.z = f2bf(f1.x) | (f2bf(f1.y) << 16);
            val.w = f2bf(f1.z) | (f2bf(f1.w) << 16);
        }
        *(uint4*)(pa + (size_t)idx * 8) = val;
        return;
    }
    idx -= na;
    if (idx < 16384) {
        // pack W into MFMA B-fragment order (bf16): [mat][ng][s16][lane] x 16B
        int lane = idx & 63;
        int s16  = (idx >> 6) & 15;
        int ng   = (idx >> 10) & 7;
        int mat  = idx >> 13;
        const float* W = mat ? Wr : Wl;
        int n  = ng * 32 + (lane & 31);
        int k0 = s16 * 16 + (lane >> 5) * 4;
        uint4 val;
        val.x = f2bf(W[(size_t)(k0 + 0) * DD + n]) | (f2bf(W[(size_t)(k0 + 1) * DD + n]) << 16);
        val.y = f2bf(W[(size_t)(k0 + 2) * DD + n]) | (f2bf(W[(size_t)(k0 + 3) * DD + n]) << 16);
        val.z = f2bf(W[(size_t)(k0 + 8) * DD + n]) | (f2bf(W[(size_t)(k0 + 9) * DD + n]) << 16);
        val.w = f2bf(W[(size_t)(k0 +10) * DD + n]) | (f2bf(W[(size_t)(k0 +11) * DD + n]) << 16);
        *(uint4*)(pw + (size_t)idx * 8) = val;
    }
}

// ---------------- mid: scatter blocks first, then mm tiles ------------------
__global__ __launch_bounds__(256, 4) void mid_kernel(const ushort* __restrict__ pa,
                                                     const ushort* __restrict__ pw,
                                                     const float* __restrict__ bl,
                                                     const float* __restrict__ br,
                                                     ushort* __restrict__ xl_h,
                                                     ushort* __restrict__ xr_h,
                                                     int N, int scat_blocks,
                                                     const int* __restrict__ src,
                                                     const int* __restrict__ dst,
                                                     const float* __restrict__ w,
                                                     int* __restrict__ counts,
                                                     int2* __restrict__ csr_sw,
                                                     int E) {
    if ((int)blockIdx.x < scat_blocks) {
        // ---- scatter: padded-CSR slot claim, one 8B store per edge ----
        int e = (int)blockIdx.x * 256 + threadIdx.x;
        if (e < E) {
            int d = dst[e];
            int pos = atomicAdd(&counts[d], 1);
            if (pos < CAP)  // safety clamp; statistically never taken
                csr_sw[((size_t)d << 6) + pos] = make_int2(src[e], __float_as_int(w[e]));
        }
        return;
    }

    // ---- MFMA GEMM, zero LDS: fragments straight from global ----
    const int bid  = (int)blockIdx.x - scat_blocks;
    const int t    = threadIdx.x;
    const int lane = t & 63;
    const int l31  = lane & 31;
    const int g    = lane >> 5;
    const int wd   = t >> 6;
    const int tile = bid >> 1, mat = bid & 1;

    const ushort* paT = pa + (size_t)tile * 2048 * 8;
    const ushort* pb  = pw + ((size_t)mat * 8192 + (size_t)(2 * wd) * 1024) * 8;

    f32x16 acc00, acc01, acc10, acc11;
    #pragma unroll
    for (int i = 0; i < 16; ++i) { acc00[i] = 0.f; acc01[i] = 0.f; acc10[i] = 0.f; acc11[i] = 0.f; }

    #pragma unroll 4
    for (int s16 = 0; s16 < 16; ++s16) {
        Frag a0, a1, b0, b1;
        a0.u4 = *(const uint4*)(paT + (size_t)((s16 * 2 + 0) * 64 + lane) * 8);
        a1.u4 = *(const uint4*)(paT + (size_t)((s16 * 2 + 1) * 64 + lane) * 8);
        b0.u4 = *(const uint4*)(pb  + (size_t)((s16     ) * 64 + lane) * 8);
        b1.u4 = *(const uint4*)(pb  + (size_t)((16 + s16) * 64 + lane) * 8);
        acc00 = __builtin_amdgcn_mfma_f32_32x32x16_bf16(a0.v, b0.v, acc00, 0, 0, 0);
        acc01 = __builtin_amdgcn_mfma_f32_32x32x16_bf16(a0.v, b1.v, acc01, 0, 0, 0);
        acc10 = __builtin_amdgcn_mfma_f32_32x32x16_bf16(a1.v, b0.v, acc10, 0, 0, 0);
        acc11 = __builtin_amdgcn_mfma_f32_32x32x16_bf16(a1.v, b1.v, acc11, 0, 0, 0);
    }

    const int n0 = wd * 64 + l31;
    const int n1 = n0 + 32;
    const float* bp = (mat == 0) ? bl : br;
    const float bv0 = bp[n0], bv1 = bp[n1];
    const int mb = tile * 64;
    ushort* dstp = (mat == 0) ? xl_h : xr_h;
    #pragma unroll
    for (int r = 0; r < 16; ++r) {
        int mloc = (r & 3) + 8 * (r >> 2) + 4 * g;
        int m0 = mb + mloc, m1 = m0 + 32;
        if (m0 < N) {
            dstp[(size_t)m0 * DD + n0] = f2h(acc00[r] + bv0);
            dstp[(size_t)m0 * DD + n1] = f2h(acc01[r] + bv1);
        }
        if (m1 < N) {
            dstp[(size_t)m1 * DD + n0] = f2h(acc10[r] + bv0);
            dstp[(size_t)m1 * DD + n1] = f2h(acc11[r] + bv1);
        }
    }
}

// ---------------- fused node kernel: one wave per node, 16 edges in flight --
// lanes 0-31 take even edges, 32-63 odd; (src,w) via same-address broadcast
// int2 loads; 8 pairs per iteration. EVERY indexed read is clamped to dm1 and
// its weight zeroed when the logical index >= deg (padded-CSR entries past
// deg are uninitialized garbage — clamp is mandatory, R13 lesson).
__global__ __launch_bounds__(256) void node_kernel(const int* __restrict__ counts,
                                                   const int2* __restrict__ csr_sw,
                                                   const ushort* __restrict__ xl_h,
                                                   const ushort* __restrict__ xr_h,
                                                   const float* __restrict__ att,
                                                   const float* __restrict__ bias,
                                                   float* __restrict__ out,
                                                   int N) {
    const int wid  = threadIdx.x >> 6;
    const int lane = threadIdx.x & 63;
    const int d = blockIdx.x * 4 + wid;
    if (d >= N) return;
    const int l31 = lane & 31;
    const int hi  = lane >> 5;
    const int c0  = l31 * 8;   // this lane's 8 channels

    const size_t beg = (size_t)d << 6;
    const int deg = min(counts[d], CAP);

    HU4 xru; xru.u4 = *(const uint4*)(xr_h + (size_t)d * DD + c0);
    const float4 af0 = *(const float4*)(att + c0);
    const float4 af1 = *(const float4*)(att + c0 + 4);
    const h2 at0 = {(_Float16)af0.x, (_Float16)af0.y};
    const h2 at1 = {(_Float16)af0.z, (_Float16)af0.w};
    const h2 at2 = {(_Float16)af1.x, (_Float16)af1.y};
    const h2 at3 = {(_Float16)af1.z, (_Float16)af1.w};
    const h2 slope = {(_Float16)NEG_SLOPE, (_Float16)NEG_SLOPE};

    float dsum = 0.f;
    h2 ac2[4];
    #pragma unroll
    for (int j = 0; j < 4; ++j) ac2[j] = (h2){(_Float16)0.f, (_Float16)0.f};

    auto body = [&](const HU4& xv, float we) {
        h2 a0 = xv.h[0] + xru.h[0];
        h2 a1 = xv.h[1] + xru.h[1];
        h2 a2 = xv.h[2] + xru.h[2];
        h2 a3 = xv.h[3] + xru.h[3];
        h2 g0 = pkmax(a0, a0 * slope);
        h2 g1 = pkmax(a1, a1 * slope);
        h2 g2 = pkmax(a2, a2 * slope);
        h2 g3 = pkmax(a3, a3 * slope);
        float p = hdot2(g3, at3, hdot2(g2, at2, hdot2(g1, at1, hdot2(g0, at0, 0.f))));
        p += __shfl_xor(p, 1);
        p += __shfl_xor(p, 2);
        float ev = we * __expf(p);
        dsum += ev;
        _Float16 evh = (_Float16)ev;
        h2 evv = {evh, evh};
        ac2[0] += evv * xv.h[0];
        ac2[1] += evv * xv.h[1];
        ac2[2] += evv * xv.h[2];
        ac2[3] += evv * xv.h[3];
    };

    const int npair = (deg + 1) >> 1;
    const int dm1   = deg - 1;
    int i = 0;
    for (; i + 8 <= npair; i += 8) {
        const int i0 = 2 * i + hi;
        int2 sw[8];
        #pragma unroll
        for (int q = 0; q < 8; ++q) sw[q] = csr_sw[beg + min(i0 + 2 * q, dm1)];
        HU4 xv[8];
        #pragma unroll
        for (int q = 0; q < 8; ++q)
            xv[q].u4 = *(const uint4*)(xl_h + (size_t)sw[q].x * DD + c0);
        #pragma unroll
        for (int q = 0; q < 8; ++q) {
            float we = (i0 + 2 * q < deg) ? __int_as_float(sw[q].y) : 0.f;
            body(xv[q], we);
        }
    }
    for (; i + 4 <= npair; i += 4) {
        const int i0 = 2 * i + hi;
        int2 sw[4];
        #pragma unroll
        for (int q = 0; q < 4; ++q) sw[q] = csr_sw[beg + min(i0 + 2 * q, dm1)];
        HU4 xv[4];
        #pragma unroll
        for (int q = 0; q < 4; ++q)
            xv[q].u4 = *(const uint4*)(xl_h + (size_t)sw[q].x * DD + c0);
        #pragma unroll
        for (int q = 0; q < 4; ++q) {
            float we = (i0 + 2 * q < deg) ? __int_as_float(sw[q].y) : 0.f;
            body(xv[q], we);
        }
    }
    for (; i < npair; ++i) {
        const int iA = 2 * i + hi;
        int2 swA = csr_sw[beg + min(iA, dm1)];
        float wA = (iA < deg) ? __int_as_float(swA.y) : 0.f;
        HU4 xvA; xvA.u4 = *(const uint4*)(xl_h + (size_t)swA.x * DD + c0);
        body(xvA, wA);
    }

    // to f32, cross-half combine (halves hold same channels, different edges)
    float ac[8];
    #pragma unroll
    for (int j = 0; j < 4; ++j) {
        ac[2 * j]     = (float)ac2[j].x;
        ac[2 * j + 1] = (float)ac2[j].y;
    }
    dsum += __shfl_xor(dsum, 32);
    #pragma unroll
    for (int j = 0; j < 8; ++j) ac[j] += __shfl_xor(ac[j], 32);
    const float inv = 1.f / (dsum + 1e-16f);

    const float4 bv = *(const float4*)(bias + c0 + 4 * hi);
    const int b = 4 * hi;
    float4 o;
    o.x = ac[b + 0] * inv + bv.x;
    o.y = ac[b + 1] * inv + bv.y;
    o.z = ac[b + 2] * inv + bv.z;
    o.w = ac[b + 3] * inv + bv.w;
    *(float4*)(out + (size_t)d * DD + c0 + 4 * hi) = o;
}

extern "C" void kernel_launch(void* const* d_in, const int* in_sizes, int n_in,
                              void* d_out, int out_size, void* d_ws, size_t ws_size,
                              hipStream_t stream) {
    const float* x    = (const float*)d_in[0];
    const int*   ei   = (const int*)  d_in[1];
    const float* w    = (const float*)d_in[2];
    const float* Wl   = (const float*)d_in[3];
    const float* bl   = (const float*)d_in[4];
    const float* Wr   = (const float*)d_in[5];
    const float* br   = (const float*)d_in[6];
    const float* att  = (const float*)d_in[7];
    const float* bias = (const float*)d_in[8];

    const int N = in_sizes[0] / DD;
    const int E = in_sizes[2];
    const int* src = ei;
    const int* dst = ei + E;

    const int Mtiles = (N + 63) / 64;
    const int Mpad   = Mtiles * 64;

    // ws: xr_h u16[N*256] | xl_h u16[N*256] | pa u16[Mpad*256] | pw u16[131072]
    //     | csr_sw int2[N*64] | counts i32[N]
    ushort* xr_h    = (ushort*)d_ws;
    ushort* xl_h    = xr_h + (size_t)N * DD;
    ushort* pa      = xl_h + (size_t)N * DD;
    ushort* pw      = pa + (size_t)Mpad * DD;
    int2*   csr_sw  = (int2*)(pw + 131072);
    int*    counts  = (int*)(csr_sw + (size_t)N * CAP);

    float* out = (float*)d_out;

    const int prep_total = N + Mpad * 32 + 16384;
    prep_kernel<<<(prep_total + 255) / 256, 256, 0, stream>>>(x, Wl, Wr,
                                                              pa, pw, counts,
                                                              N, Mpad);
    const int scat_blocks = (E + 255) / 256;
    mid_kernel <<<scat_blocks + Mtiles * 2, 256, 0, stream>>>(pa, pw, bl, br,
                                                              xl_h, xr_h,
                                                              N, scat_blocks,
                                                              src, dst, w,
                                                              counts, csr_sw, E);
    node_kernel<<<(N + 3) / 4, 256, 0, stream>>>(counts, csr_sw,
                                                 xl_h, xr_h, att, bias, out, N);
}

// Round 15
// 65.960 us; speedup vs baseline: 1.1349x; 1.1349x over previous
//
#include <hip/hip_runtime.h>
#include <hip/hip_bf16.h>
#include <math.h>

// Problem constants (from reference): D=256, H=8, C=32, H*C=256
#define DD 256
#define NHEAD 8
#define NEG_SLOPE 0.2f
#define CAP 64   // padded-CSR capacity; in-degree ~Poisson(16), P(>=64)~2e-18

typedef __attribute__((ext_vector_type(16))) float f32x16;
typedef __attribute__((ext_vector_type(8)))  short bf16x8;
typedef _Float16 h2 __attribute__((ext_vector_type(2)));

union Frag { bf16x8 v; uint4 u4; };
union HU4  { uint4 u4; h2 h[4]; };

__device__ inline uint f2bf(float f) {
    __hip_bfloat16 h = __float2bfloat16(f);
    return (uint)*(ushort*)&h;
}
__device__ inline ushort f2h(float f) {
    _Float16 h = (_Float16)f;
    return *(ushort*)&h;
}
__device__ inline h2 pkmax(h2 a, h2 b) {
    h2 d;
    asm("v_pk_max_f16 %0, %1, %2" : "=v"(d) : "v"(a), "v"(b));
    return d;
}
__device__ inline float hdot2(h2 a, h2 b, float c) {
#if __has_builtin(__builtin_amdgcn_fdot2)
    return __builtin_amdgcn_fdot2(a, b, c, false);
#else
    return c + (float)a.x * (float)b.x + (float)a.y * (float)b.y;
#endif
}

// ---------------- fused prep: zero counts | pack_x | pack_w -----------------
__global__ __launch_bounds__(256) void prep_kernel(const float* __restrict__ x,
                                                   const float* __restrict__ Wl,
                                                   const float* __restrict__ Wr,
                                                   ushort* __restrict__ pa,
                                                   ushort* __restrict__ pw,
                                                   int* __restrict__ counts,
                                                   int N, int Mpad) {
    int idx = blockIdx.x * 256 + threadIdx.x;
    if (idx < N) { counts[idx] = 0; return; }
    idx -= N;
    const int na = Mpad * 32;
    if (idx < na) {
        // pack x into MFMA A-fragment order (bf16): [tile][s16][mi][lane] x 16B
        int lane = idx & 63;
        int mi   = (idx >> 6) & 1;
        int s16  = (idx >> 7) & 15;
        int tile = idx >> 11;
        int m = tile * 64 + mi * 32 + (lane & 31);
        int g = lane >> 5;
        uint4 val = {0u, 0u, 0u, 0u};
        if (m < N) {
            const float* xp = x + (size_t)m * DD + s16 * 16 + g * 4;
            float4 f0 = *(const float4*)xp;
            float4 f1 = *(const float4*)(xp + 8);
            val.x = f2bf(f0.x) | (f2bf(f0.y) << 16);
            val.y = f2bf(f0.z) | (f2bf(f0.w) << 16);
            val.z = f2bf(f1.x) | (f2bf(f1.y) << 16);
            val.w = f2bf(f1.z) | (f2bf(f1.w) << 16);
        }
        *(uint4*)(pa + (size_t)idx * 8) = val;
        return;
    }
    idx -= na;
    if (idx < 16384) {
        // pack W into MFMA B-fragment order (bf16): [mat][ng][s16][lane] x 16B
        int lane = idx & 63;
        int s16  = (idx >> 6) & 15;
        int ng   = (idx >> 10) & 7;
        int mat  = idx >> 13;
        const float* W = mat ? Wr : Wl;
        int n  = ng * 32 + (lane & 31);
        int k0 = s16 * 16 + (lane >> 5) * 4;
        uint4 val;
        val.x = f2bf(W[(size_t)(k0 + 0) * DD + n]) | (f2bf(W[(size_t)(k0 + 1) * DD + n]) << 16);
        val.y = f2bf(W[(size_t)(k0 + 2) * DD + n]) | (f2bf(W[(size_t)(k0 + 3) * DD + n]) << 16);
        val.z = f2bf(W[(size_t)(k0 + 8) * DD + n]) | (f2bf(W[(size_t)(k0 + 9) * DD + n]) << 16);
        val.w = f2bf(W[(size_t)(k0 +10) * DD + n]) | (f2bf(W[(size_t)(k0 +11) * DD + n]) << 16);
        *(uint4*)(pw + (size_t)idx * 8) = val;
    }
}

// ---------------- mid: mm tiles (blocks [0, 2*Mtiles)) + scatter (rest) -----
// mm and scatter both depend only on prep and not on each other; fusing them
// into one grid overlaps MFMA/L2 work with atomic-latency work and removes a
// launch gap. Bodies are identical to the R11-proven versions.
__global__ __launch_bounds__(256, 4) void mid_kernel(const ushort* __restrict__ pa,
                                                     const ushort* __restrict__ pw,
                                                     const float* __restrict__ bl,
                                                     const float* __restrict__ br,
                                                     ushort* __restrict__ xl_h,
                                                     ushort* __restrict__ xr_h,
                                                     int N, int Mtiles,
                                                     const int* __restrict__ src,
                                                     const int* __restrict__ dst,
                                                     const float* __restrict__ w,
                                                     int* __restrict__ counts,
                                                     int2* __restrict__ csr_sw,
                                                     int E) {
    const int nmm = Mtiles * 2;
    if ((int)blockIdx.x >= nmm) {
        // ---- scatter: padded-CSR slot claim, one 8B store per edge ----
        int e = ((int)blockIdx.x - nmm) * 256 + threadIdx.x;
        if (e < E) {
            int d = dst[e];
            int pos = atomicAdd(&counts[d], 1);
            if (pos < CAP)  // safety clamp; statistically never taken
                csr_sw[((size_t)d << 6) + pos] = make_int2(src[e], __float_as_int(w[e]));
        }
        return;
    }

    // ---- MFMA GEMM, zero LDS: fragments straight from global ----
    const int t    = threadIdx.x;
    const int lane = t & 63;
    const int l31  = lane & 31;
    const int g    = lane >> 5;
    const int wd   = t >> 6;
    const int tile = blockIdx.x >> 1, mat = blockIdx.x & 1;

    const ushort* paT = pa + (size_t)tile * 2048 * 8;
    const ushort* pb  = pw + ((size_t)mat * 8192 + (size_t)(2 * wd) * 1024) * 8;

    f32x16 acc00, acc01, acc10, acc11;
    #pragma unroll
    for (int i = 0; i < 16; ++i) { acc00[i] = 0.f; acc01[i] = 0.f; acc10[i] = 0.f; acc11[i] = 0.f; }

    #pragma unroll 4
    for (int s16 = 0; s16 < 16; ++s16) {
        Frag a0, a1, b0, b1;
        a0.u4 = *(const uint4*)(paT + (size_t)((s16 * 2 + 0) * 64 + lane) * 8);
        a1.u4 = *(const uint4*)(paT + (size_t)((s16 * 2 + 1) * 64 + lane) * 8);
        b0.u4 = *(const uint4*)(pb  + (size_t)((s16     ) * 64 + lane) * 8);
        b1.u4 = *(const uint4*)(pb  + (size_t)((16 + s16) * 64 + lane) * 8);
        acc00 = __builtin_amdgcn_mfma_f32_32x32x16_bf16(a0.v, b0.v, acc00, 0, 0, 0);
        acc01 = __builtin_amdgcn_mfma_f32_32x32x16_bf16(a0.v, b1.v, acc01, 0, 0, 0);
        acc10 = __builtin_amdgcn_mfma_f32_32x32x16_bf16(a1.v, b0.v, acc10, 0, 0, 0);
        acc11 = __builtin_amdgcn_mfma_f32_32x32x16_bf16(a1.v, b1.v, acc11, 0, 0, 0);
    }

    const int n0 = wd * 64 + l31;
    const int n1 = n0 + 32;
    const float* bp = (mat == 0) ? bl : br;
    const float bv0 = bp[n0], bv1 = bp[n1];
    const int mb = tile * 64;
    ushort* dstp = (mat == 0) ? xl_h : xr_h;
    #pragma unroll
    for (int r = 0; r < 16; ++r) {
        int mloc = (r & 3) + 8 * (r >> 2) + 4 * g;
        int m0 = mb + mloc, m1 = m0 + 32;
        if (m0 < N) {
            dstp[(size_t)m0 * DD + n0] = f2h(acc00[r] + bv0);
            dstp[(size_t)m0 * DD + n1] = f2h(acc01[r] + bv1);
        }
        if (m1 < N) {
            dstp[(size_t)m1 * DD + n0] = f2h(acc10[r] + bv0);
            dstp[(size_t)m1 * DD + n1] = f2h(acc11[r] + bv1);
        }
    }
}

// ---------------- fused node kernel: one wave per node, 8 edges in flight ---
// lanes 0-31 take even edges, 32-63 odd; (src,w) via same-address broadcast
// int2 loads; 4 pairs per iteration (4 indep int2 loads, then 4 indep 16B
// gathers) for memory-level parallelism; f16 packed-fma aggregation.
__global__ __launch_bounds__(256) void node_kernel(const int* __restrict__ counts,
                                                   const int2* __restrict__ csr_sw,
                                                   const ushort* __restrict__ xl_h,
                                                   const ushort* __restrict__ xr_h,
                                                   const float* __restrict__ att,
                                                   const float* __restrict__ bias,
                                                   float* __restrict__ out,
                                                   int N) {
    const int wid  = threadIdx.x >> 6;
    const int lane = threadIdx.x & 63;
    const int d = blockIdx.x * 4 + wid;
    if (d >= N) return;
    const int l31 = lane & 31;
    const int hi  = lane >> 5;
    const int c0  = l31 * 8;   // this lane's 8 channels

    const size_t beg = (size_t)d << 6;
    const int deg = min(counts[d], CAP);

    HU4 xru; xru.u4 = *(const uint4*)(xr_h + (size_t)d * DD + c0);
    const float4 af0 = *(const float4*)(att + c0);
    const float4 af1 = *(const float4*)(att + c0 + 4);
    const h2 at0 = {(_Float16)af0.x, (_Float16)af0.y};
    const h2 at1 = {(_Float16)af0.z, (_Float16)af0.w};
    const h2 at2 = {(_Float16)af1.x, (_Float16)af1.y};
    const h2 at3 = {(_Float16)af1.z, (_Float16)af1.w};
    const h2 slope = {(_Float16)NEG_SLOPE, (_Float16)NEG_SLOPE};

    float dsum = 0.f;
    h2 ac2[4];
    #pragma unroll
    for (int j = 0; j < 4; ++j) ac2[j] = (h2){(_Float16)0.f, (_Float16)0.f};

    auto body = [&](const HU4& xv, float we) {
        h2 a0 = xv.h[0] + xru.h[0];
        h2 a1 = xv.h[1] + xru.h[1];
        h2 a2 = xv.h[2] + xru.h[2];
        h2 a3 = xv.h[3] + xru.h[3];
        h2 g0 = pkmax(a0, a0 * slope);
        h2 g1 = pkmax(a1, a1 * slope);
        h2 g2 = pkmax(a2, a2 * slope);
        h2 g3 = pkmax(a3, a3 * slope);
        float p = hdot2(g3, at3, hdot2(g2, at2, hdot2(g1, at1, hdot2(g0, at0, 0.f))));
        p += __shfl_xor(p, 1);
        p += __shfl_xor(p, 2);
        float ev = we * __expf(p);
        dsum += ev;
        _Float16 evh = (_Float16)ev;
        h2 evv = {evh, evh};
        ac2[0] += evv * xv.h[0];
        ac2[1] += evv * xv.h[1];
        ac2[2] += evv * xv.h[2];
        ac2[3] += evv * xv.h[3];
    };

    const int npair = (deg + 1) >> 1;
    const int dm1   = deg - 1;
    int i = 0;
    for (; i + 4 <= npair; i += 4) {
        const int iA = 2 * i + hi;
        const int iB = iA + 2, iC = iA + 4, iD = iA + 6;
        int2 swA = csr_sw[beg + min(iA, dm1)];
        int2 swB = csr_sw[beg + min(iB, dm1)];
        int2 swC = csr_sw[beg + min(iC, dm1)];
        int2 swD = csr_sw[beg + min(iD, dm1)];
        float wA = (iA < deg) ? __int_as_float(swA.y) : 0.f;
        float wB = (iB < deg) ? __int_as_float(swB.y) : 0.f;
        float wC = (iC < deg) ? __int_as_float(swC.y) : 0.f;
        float wD = (iD < deg) ? __int_as_float(swD.y) : 0.f;
        HU4 xvA; xvA.u4 = *(const uint4*)(xl_h + (size_t)swA.x * DD + c0);
        HU4 xvB; xvB.u4 = *(const uint4*)(xl_h + (size_t)swB.x * DD + c0);
        HU4 xvC; xvC.u4 = *(const uint4*)(xl_h + (size_t)swC.x * DD + c0);
        HU4 xvD; xvD.u4 = *(const uint4*)(xl_h + (size_t)swD.x * DD + c0);
        body(xvA, wA);
        body(xvB, wB);
        body(xvC, wC);
        body(xvD, wD);
    }
    for (; i < npair; ++i) {
        const int iA = 2 * i + hi;
        int2 swA = csr_sw[beg + min(iA, dm1)];
        float wA = (iA < deg) ? __int_as_float(swA.y) : 0.f;
        HU4 xvA; xvA.u4 = *(const uint4*)(xl_h + (size_t)swA.x * DD + c0);
        body(xvA, wA);
    }

    // to f32, cross-half combine (halves hold same channels, different edges)
    float ac[8];
    #pragma unroll
    for (int j = 0; j < 4; ++j) {
        ac[2 * j]     = (float)ac2[j].x;
        ac[2 * j + 1] = (float)ac2[j].y;
    }
    dsum += __shfl_xor(dsum, 32);
    #pragma unroll
    for (int j = 0; j < 8; ++j) ac[j] += __shfl_xor(ac[j], 32);
    const float inv = 1.f / (dsum + 1e-16f);

    const float4 bv = *(const float4*)(bias + c0 + 4 * hi);
    const int b = 4 * hi;
    float4 o;
    o.x = ac[b + 0] * inv + bv.x;
    o.y = ac[b + 1] * inv + bv.y;
    o.z = ac[b + 2] * inv + bv.z;
    o.w = ac[b + 3] * inv + bv.w;
    *(float4*)(out + (size_t)d * DD + c0 + 4 * hi) = o;
}

extern "C" void kernel_launch(void* const* d_in, const int* in_sizes, int n_in,
                              void* d_out, int out_size, void* d_ws, size_t ws_size,
                              hipStream_t stream) {
    const float* x    = (const float*)d_in[0];
    const int*   ei   = (const int*)  d_in[1];
    const float* w    = (const float*)d_in[2];
    const float* Wl   = (const float*)d_in[3];
    const float* bl   = (const float*)d_in[4];
    const float* Wr   = (const float*)d_in[5];
    const float* br   = (const float*)d_in[6];
    const float* att  = (const float*)d_in[7];
    const float* bias = (const float*)d_in[8];

    const int N = in_sizes[0] / DD;
    const int E = in_sizes[2];
    const int* src = ei;
    const int* dst = ei + E;

    const int Mtiles = (N + 63) / 64;
    const int Mpad   = Mtiles * 64;

    // ws: xr_h u16[N*256] | xl_h u16[N*256] | pa u16[Mpad*256] | pw u16[131072]
    //     | csr_sw int2[N*64] | counts i32[N]
    ushort* xr_h    = (ushort*)d_ws;
    ushort* xl_h    = xr_h + (size_t)N * DD;
    ushort* pa      = xl_h + (size_t)N * DD;
    ushort* pw      = pa + (size_t)Mpad * DD;
    int2*   csr_sw  = (int2*)(pw + 131072);
    int*    counts  = (int*)(csr_sw + (size_t)N * CAP);

    float* out = (float*)d_out;

    const int prep_total = N + Mpad * 32 + 16384;
    prep_kernel<<<(prep_total + 255) / 256, 256, 0, stream>>>(x, Wl, Wr,
                                                              pa, pw, counts,
                                                              N, Mpad);
    const int scat_blocks = (E + 255) / 256;
    mid_kernel <<<Mtiles * 2 + scat_blocks, 256, 0, stream>>>(pa, pw, bl, br,
                                                              xl_h, xr_h,
                                                              N, Mtiles,
                                                              src, dst, w,
                                                              counts, csr_sw, E);
    node_kernel<<<(N + 3) / 4, 256, 0, stream>>>(counts, csr_sw,
                                                 xl_h, xr_h, att, bias, out, N);
}